// Round 3
// baseline (17736.423 us; speedup 1.0000x reference)
//
#include <hip/hip_runtime.h>
#include <stdint.h>

// Problem dims
#define B_    64
#define T_    2048
#define IN_   64
#define H_    512
#define H2_   1024
#define OUT_  32
#define KTOT  576          // IN_ + H_

// Grid: 256 blocks = 8 batch-groups x 32 col-groups, 256 threads.
#define NBG   8
#define NCG   32
#define NTHR  256
#define BPG   8            // batches per group
#define KSL   18           // k per slice (32 slices x 18 = 576)
#define RS    12           // bufA row stride in floats

// ws layout (32-bit words)
// Exchange data: epoch-tagged (value,epoch) pairs; pair p = bg*4096+col*8+b
// at words BUF_BASE + slab + 2p (+1 = epoch). Flags are HINTS only (throttle
// polling); correctness comes from the per-pair epoch verify.
#define FLAG_STRIDE 16
#define ABORT_IDX   0
#define FLAGS_OFF   16
#define FLAG_WORDS  (NBG * 2 * NCG * FLAG_STRIDE)   // 8192
#define BUF_BASE    (FLAGS_OFF + FLAG_WORDS)        // 8208 (64B-aligned)
#define PAIRS_BG    (H_ * BPG)                      // 4096 pairs per bg
#define PSLAB       (NBG * PAIRS_BG * 2)            // 65536 words per slab

// ---- MALL-resident exchange primitives (all device-scope sc1) ----
// Publish one (value,epoch) pair: single 8B MALL atomic swap, fire-and-forget
// (NO drain -- consumers verify the epoch in the data itself). 8B atomicity
// guarantees value+epoch arrive together.
__device__ __forceinline__ void gpub2(float* p, float v, unsigned e) {
  unsigned long long q =
      ((unsigned long long)e << 32) | (unsigned long long)__float_as_uint(v);
  asm volatile("global_atomic_swap_x2 %0, %1, off sc1"
               :: "v"(p), "v"(q) : "memory");
}
// Flag hint publish: fire-and-forget 4B swap (unordered vs data; that's fine).
__device__ __forceinline__ void gpubu(unsigned* p, unsigned v) {
  asm volatile("global_atomic_swap %0, %1, off sc1"
               :: "v"(p), "v"(v) : "memory");
}
// Coherent 4B flag poll load.
__device__ __forceinline__ unsigned gpollu(const unsigned* p) {
  unsigned v;
  asm volatile("global_load_dword %0, %1, off sc0 sc1\n\ts_waitcnt vmcnt(0)"
               : "=v"(v) : "v"(p) : "memory");
  return v;
}

// Verified bulk load: 16 (value,epoch) pairs = two 64B rows, 8 dwordx4 in
// flight, one wait; retry until every epoch == target. With the flag gate in
// front this nearly always succeeds on the first try.
__device__ __forceinline__ bool poll_slab(
    const float* b0, const float* b1, unsigned target, unsigned* abort_w,
    float4& r0, float4& r1, float4& r2, float4& r3,
    float4& r4, float4& r5, float4& r6, float4& r7) {
  int polls = 0;
  for (;;) {
    asm volatile(
        "global_load_dwordx4 %0, %8, off sc0 sc1\n\t"
        "global_load_dwordx4 %1, %8, off offset:16 sc0 sc1\n\t"
        "global_load_dwordx4 %2, %8, off offset:32 sc0 sc1\n\t"
        "global_load_dwordx4 %3, %8, off offset:48 sc0 sc1\n\t"
        "global_load_dwordx4 %4, %9, off sc0 sc1\n\t"
        "global_load_dwordx4 %5, %9, off offset:16 sc0 sc1\n\t"
        "global_load_dwordx4 %6, %9, off offset:32 sc0 sc1\n\t"
        "global_load_dwordx4 %7, %9, off offset:48 sc0 sc1\n\t"
        "s_waitcnt vmcnt(0)"
        : "=&v"(r0), "=&v"(r1), "=&v"(r2), "=&v"(r3),
          "=&v"(r4), "=&v"(r5), "=&v"(r6), "=&v"(r7)
        : "v"(b0), "v"(b1)
        : "memory");
    unsigned m =
        (__float_as_uint(r0.y) ^ target) | (__float_as_uint(r0.w) ^ target) |
        (__float_as_uint(r1.y) ^ target) | (__float_as_uint(r1.w) ^ target) |
        (__float_as_uint(r2.y) ^ target) | (__float_as_uint(r2.w) ^ target) |
        (__float_as_uint(r3.y) ^ target) | (__float_as_uint(r3.w) ^ target) |
        (__float_as_uint(r4.y) ^ target) | (__float_as_uint(r4.w) ^ target) |
        (__float_as_uint(r5.y) ^ target) | (__float_as_uint(r5.w) ^ target) |
        (__float_as_uint(r6.y) ^ target) | (__float_as_uint(r6.w) ^ target) |
        (__float_as_uint(r7.y) ^ target) | (__float_as_uint(r7.w) ^ target);
    if (m == 0u) return true;
    __builtin_amdgcn_s_sleep(1);
    if ((++polls & 63) == 0) {
      if (__hip_atomic_load(abort_w, __ATOMIC_RELAXED, __HIP_MEMORY_SCOPE_AGENT) != 0u ||
          polls > 500000) {
        __hip_atomic_store(abort_w, 1u, __ATOMIC_RELAXED, __HIP_MEMORY_SCOPE_AGENT);
        return false;
      }
    }
  }
}

// Cheap flag-hint wait: 32 lanes of wave 0 each poll a distinct 64B line
// (2KB/round -- round-0's proven-benign traffic level).
__device__ __forceinline__ bool gbar_wait(unsigned* base, unsigned target,
                                          unsigned* abort_w) {
  __shared__ int s_ok;
  const int tid = threadIdx.x;
  int ok = 1;
  if (tid < NCG) {
    const unsigned* f = base + tid * FLAG_STRIDE;
    int polls = 0;
    while (gpollu(f) < target) {
      __builtin_amdgcn_s_sleep(1);
      if ((++polls & 255) == 0) {
        if (__hip_atomic_load(abort_w, __ATOMIC_RELAXED, __HIP_MEMORY_SCOPE_AGENT) != 0u ||
            polls > 2000000) {
          __hip_atomic_store(abort_w, 1u, __ATOMIC_RELAXED, __HIP_MEMORY_SCOPE_AGENT);
          ok = 0;
          break;
        }
      }
    }
  }
  if (tid < 64) {
    unsigned long long bad = __ballot(ok == 0);
    if (tid == 0) s_ok = (bad == 0ull) ? 1 : 0;
  }
  __syncthreads();
  __atomic_signal_fence(__ATOMIC_ACQUIRE);  // compiler reordering guard only
  return s_ok != 0;
}

__global__ __launch_bounds__(256) void gru_init(float* ws, const float* __restrict__ x0) {
  int i = blockIdx.x * blockDim.x + threadIdx.x;
  int stride = gridDim.x * blockDim.x;
  unsigned* w = (unsigned*)ws;
  for (int k = i; k < BUF_BASE; k += stride) w[k] = 0u;   // abort + flags
  unsigned* rest = w + BUF_BASE + PSLAB;   // xg1 + xfg slabs: epoch 0 (stale)
  for (int k = i; k < 2 * PSLAB; k += stride) rest[k] = 0u;
  // xg0 pairs: (x0 value, epoch 0) -- iteration 0 verifies epoch 0.
  for (int p = i; p < NBG * PAIRS_BG; p += stride) {
    int bg = p >> 12, col = (p >> 3) & (H_ - 1), b = p & 7;
    ws[BUF_BASE + 2 * p] = x0[(bg * 8 + b) * H_ + col];
    w[BUF_BASE + 2 * p + 1] = 0u;
  }
}

__global__ __launch_bounds__(NTHR, 1) void gru_main(
    const float* __restrict__ u, const float* __restrict__ kfz,
    const float* __restrict__ bfz, const float* __restrict__ kr,
    const float* __restrict__ br, const float* __restrict__ wout,
    const float* __restrict__ bout, float* __restrict__ out, float* ws) {
  unsigned* wsu = (unsigned*)ws;
  unsigned* flags = wsu + FLAGS_OFF;
  unsigned* abort_w = wsu + ABORT_IDX;
  float* xg0p = ws + BUF_BASE;
  float* xg1p = xg0p + PSLAB;
  float* xfgp = xg1p + PSLAB;

  const int bg  = blockIdx.x & 7;
  const int cg  = blockIdx.x >> 3;   // column group 0..31
  const int tid = threadIdx.x;
  const int w   = tid >> 6;          // wave 0..3
  const int l   = tid & 63;
  const int cq  = l & 7;             // col-quad 0..7
  const int g   = l >> 3;            // in-wave k-slice 0..7
  const int kb  = (w * 8 + g) * KSL; // this thread's k base (18 k's)
  const int fc  = tid >> 3;          // finalize col 0..31
  const int fb  = tid & 7;           // finalize batch 0..7
  const int yb  = tid >> 5;          // y batch 0..7
  const int yq  = tid & 31;          // y k-slice 0..31

  unsigned* slotA = flags + ((bg * 2 + 0) * NCG + cg) * FLAG_STRIDE;
  unsigned* slotB = flags + ((bg * 2 + 1) * NCG + cg) * FLAG_STRIDE;
  unsigned* baseA = flags + (bg * 2 + 0) * NCG * FLAG_STRIDE;
  unsigned* baseB = flags + (bg * 2 + 1) * NCG * FLAG_STRIDE;

  __shared__ float bufA[KTOT * RS];  // [k][12]: u_t(k<64) | x or f*x
  __shared__ float pA[4 * 32 * RS];
  __shared__ float pB[4 * 16 * RS];
  __shared__ float rbuf[16 * 8];
  __shared__ int s_bad;

  // ---- one-time: weights into registers ----
  float wA[KSL][4];
#pragma unroll
  for (int i = 0; i < KSL; ++i)
#pragma unroll
    for (int m = 0; m < 4; ++m) {
      int c = 4 * cq + m;
      int gcol = (c < 16) ? (16 * cg + c) : (512 + 16 * cg + (c - 16));
      wA[i][m] = kfz[(size_t)(kb + i) * H2_ + gcol];
    }
  float wB[KSL][2];
#pragma unroll
  for (int i = 0; i < KSL; ++i)
#pragma unroll
    for (int m = 0; m < 2; ++m)
      wB[i][m] = kr[(size_t)(kb + i) * H_ + (16 * cg + 2 * cq + m)];
  float wy[16];
#pragma unroll
  for (int i = 0; i < 16; ++i) wy[i] = wout[cg * H_ + (yq + 32 * i)];
  const float by = bout[cg];
  const int fzc = (fc < 16) ? (16 * cg + fc) : (512 + 16 * cg + (fc - 16));
  const float biasA = bfz[fzc];
  const float biasB = (tid < 128) ? br[16 * cg + fc] : 0.0f;

  float zreg = 0.0f, xoldz = 0.0f;

  if (tid == 0) s_bad = 0;
  // u_t=0 into LDS (later steps prefetched during the phase-B publish window)
  {
    int k2 = tid & 31, b = tid >> 5;
    float2 uv = *(const float2*)&u[((size_t)(bg * 8 + b) * T_) * IN_ + 2 * k2];
    bufA[(2 * k2) * RS + b] = uv.x;
    bufA[(2 * k2 + 1) * RS + b] = uv.y;
  }
  __syncthreads();

  for (int t = 0; t < T_; ++t) {
    const float* xcp = (t & 1) ? xg1p : xg0p;
    float*       xnp = (t & 1) ? xg0p : xg1p;

    // ---- phase A staging: flag hint (cheap), then ONE verified bulk load ----
    if (!gbar_wait(baseB, (unsigned)t, abort_w)) return;   // t=0: trivially true
    {
      const float* b0 = xcp + 2 * ((size_t)bg * PAIRS_BG + (size_t)tid * 8);
      const float* b1 = b0 + 4096;   // col tid+256
      float4 r0, r1, r2, r3, r4, r5, r6, r7;
      bool ok = poll_slab(b0, b1, (unsigned)t, abort_w,
                          r0, r1, r2, r3, r4, r5, r6, r7);
      if (!ok) s_bad = 1;
      __syncthreads();               // also fences prior readers of bufA rows 64+
      if (s_bad) return;
      *(float4*)&bufA[(64 + tid) * RS]       = make_float4(r0.x, r0.z, r1.x, r1.z);
      *(float4*)&bufA[(64 + tid) * RS + 4]   = make_float4(r2.x, r2.z, r3.x, r3.z);
      *(float4*)&bufA[(64 + tid + 256) * RS]     = make_float4(r4.x, r4.z, r5.x, r5.z);
      *(float4*)&bufA[(64 + tid + 256) * RS + 4] = make_float4(r6.x, r6.z, r7.x, r7.z);
    }
    __syncthreads();

    // ---- phase A core: fz partials for 4 cols x 8 batches over 18 k ----
    float acc[4][8] = {};
#pragma unroll
    for (int i = 0; i < KSL; ++i) {
      const float* xr = &bufA[(kb + i) * RS];
      float4 x0 = *(const float4*)xr;
      float4 x1 = *(const float4*)(xr + 4);
#pragma unroll
      for (int m = 0; m < 4; ++m) {
        float wv = wA[i][m];
        acc[m][0] += wv * x0.x; acc[m][1] += wv * x0.y;
        acc[m][2] += wv * x0.z; acc[m][3] += wv * x0.w;
        acc[m][4] += wv * x1.x; acc[m][5] += wv * x1.y;
        acc[m][6] += wv * x1.z; acc[m][7] += wv * x1.w;
      }
    }

    // ---- reduce A ----
#pragma unroll
    for (int m = 0; m < 4; ++m)
#pragma unroll
      for (int b = 0; b < 8; ++b) {
        acc[m][b] += __shfl_xor(acc[m][b], 8);
        acc[m][b] += __shfl_xor(acc[m][b], 16);
        acc[m][b] += __shfl_xor(acc[m][b], 32);
      }
    if (g == 0) {
#pragma unroll
      for (int m = 0; m < 4; ++m) {
        float* p = &pA[(w * 32 + 4 * cq + m) * RS];
        *(float4*)p = make_float4(acc[m][0], acc[m][1], acc[m][2], acc[m][3]);
        *(float4*)(p + 4) = make_float4(acc[m][4], acc[m][5], acc[m][6], acc[m][7]);
      }
    }
    __syncthreads();

    // ---- finalize A: sigmoid; fire (f*x, t+1) pairs + flag hint; stash z ----
    {
      float s = pA[(0 * 32 + fc) * RS + fb] + pA[(1 * 32 + fc) * RS + fb] +
                pA[(2 * 32 + fc) * RS + fb] + pA[(3 * 32 + fc) * RS + fb] + biasA;
      float sig = 1.0f / (1.0f + __expf(-s));
      if (fc < 16) {
        float xo = bufA[(64 + 16 * cg + fc) * RS + fb];
        float* p = &xfgp[2 * ((size_t)bg * PAIRS_BG + (size_t)(16 * cg + fc) * 8 + fb)];
        gpub2(p, sig * xo, (unsigned)(t + 1));
        if (tid == 0) gpubu(slotA, (unsigned)(t + 1));   // hint, fire-and-forget
      } else {
        zreg = sig;
        xoldz = bufA[(64 + 16 * cg + (fc - 16)) * RS + fb];
      }
    }

    // ---- y_t = x_t @ wout[cg]: overlaps the in-flight publishes ----
    {
      float yp = 0.0f;
#pragma unroll
      for (int i = 0; i < 16; ++i)
        yp += wy[i] * bufA[(64 + yq + 32 * i) * RS + yb];
      yp += __shfl_xor(yp, 1);  yp += __shfl_xor(yp, 2);
      yp += __shfl_xor(yp, 4);  yp += __shfl_xor(yp, 8);
      yp += __shfl_xor(yp, 16);
      if (yq == 0)
        out[((size_t)(bg * 8 + yb) * T_ + t) * OUT_ + cg] = yp + by;
    }

    // ---- phase B staging: flag hint, then verified bulk load of f*x ----
    if (!gbar_wait(baseA, (unsigned)(t + 1), abort_w)) return;
    {
      const float* b0 = xfgp + 2 * ((size_t)bg * PAIRS_BG + (size_t)tid * 8);
      const float* b1 = b0 + 4096;
      float4 r0, r1, r2, r3, r4, r5, r6, r7;
      bool ok = poll_slab(b0, b1, (unsigned)(t + 1), abort_w,
                          r0, r1, r2, r3, r4, r5, r6, r7);
      if (!ok) s_bad = 1;
      __syncthreads();               // all finalize-A / y reads of bufA done
      if (s_bad) return;
      *(float4*)&bufA[(64 + tid) * RS]       = make_float4(r0.x, r0.z, r1.x, r1.z);
      *(float4*)&bufA[(64 + tid) * RS + 4]   = make_float4(r2.x, r2.z, r3.x, r3.z);
      *(float4*)&bufA[(64 + tid + 256) * RS]     = make_float4(r4.x, r4.z, r5.x, r5.z);
      *(float4*)&bufA[(64 + tid + 256) * RS + 4] = make_float4(r6.x, r6.z, r7.x, r7.z);
    }
    __syncthreads();

    // ---- phase B core: r partials for 2 cols x 8 batches ----
    float acc2[2][8] = {};
#pragma unroll
    for (int i = 0; i < KSL; ++i) {
      const float* xr = &bufA[(kb + i) * RS];
      float4 x0 = *(const float4*)xr;
      float4 x1 = *(const float4*)(xr + 4);
#pragma unroll
      for (int m = 0; m < 2; ++m) {
        float wv = wB[i][m];
        acc2[m][0] += wv * x0.x; acc2[m][1] += wv * x0.y;
        acc2[m][2] += wv * x0.z; acc2[m][3] += wv * x0.w;
        acc2[m][4] += wv * x1.x; acc2[m][5] += wv * x1.y;
        acc2[m][6] += wv * x1.z; acc2[m][7] += wv * x1.w;
      }
    }
#pragma unroll
    for (int m = 0; m < 2; ++m)
#pragma unroll
      for (int b = 0; b < 8; ++b) {
        acc2[m][b] += __shfl_xor(acc2[m][b], 8);
        acc2[m][b] += __shfl_xor(acc2[m][b], 16);
        acc2[m][b] += __shfl_xor(acc2[m][b], 32);
      }
    if (g == 0) {
#pragma unroll
      for (int m = 0; m < 2; ++m) {
        float* p = &pB[(w * 16 + 2 * cq + m) * RS];
        *(float4*)p = make_float4(acc2[m][0], acc2[m][1], acc2[m][2], acc2[m][3]);
        *(float4*)(p + 4) = make_float4(acc2[m][4], acc2[m][5], acc2[m][6], acc2[m][7]);
      }
    }
    __syncthreads();

    // ---- finalize B: tanh -> rbuf ----
    if (tid < 128) {
      float s = pB[(0 * 16 + fc) * RS + fb] + pB[(1 * 16 + fc) * RS + fb] +
                pB[(2 * 16 + fc) * RS + fb] + pB[(3 * 16 + fc) * RS + fb] + biasB;
      float e = __expf(2.0f * s);
      rbuf[fc * 8 + fb] = 1.0f - 2.0f / (1.0f + e);
    }
    __syncthreads();

    // ---- update: fire (x + z*(r-x), t+1) pairs + flag hint ----
    if (tid >= 128) {
      float r = rbuf[(fc - 16) * 8 + fb];
      float xn = xoldz + zreg * (r - xoldz);
      float* p = &xnp[2 * ((size_t)bg * PAIRS_BG + (size_t)(16 * cg + (fc - 16)) * 8 + fb)];
      gpub2(p, xn, (unsigned)(t + 1));
      if (tid == 128) gpubu(slotB, (unsigned)(t + 1));   // hint, fire-and-forget
    }

    // ---- prefetch u_{t+1} into LDS; overlaps peers' publishes ----
    if (t + 1 < T_) {
      int k2 = tid & 31, b = tid >> 5;
      float2 uv = *(const float2*)&u[((size_t)(bg * 8 + b) * T_ + (t + 1)) * IN_ + 2 * k2];
      bufA[(2 * k2) * RS + b] = uv.x;
      bufA[(2 * k2 + 1) * RS + b] = uv.y;
    }
    // no barrier here: next iteration's staging sync orders everything
  }
}

extern "C" void kernel_launch(void* const* d_in, const int* in_sizes, int n_in,
                              void* d_out, int out_size, void* d_ws, size_t ws_size,
                              hipStream_t stream) {
  const float* u    = (const float*)d_in[0];
  const float* x0   = (const float*)d_in[1];
  const float* kfz  = (const float*)d_in[2];
  const float* bfz  = (const float*)d_in[3];
  const float* kr   = (const float*)d_in[4];
  const float* br   = (const float*)d_in[5];
  const float* wout = (const float*)d_in[6];
  const float* bout = (const float*)d_in[7];
  float* out = (float*)d_out;
  float* ws  = (float*)d_ws;

  hipLaunchKernelGGL(gru_init, dim3(64), dim3(256), 0, stream, ws, x0);
  hipLaunchKernelGGL(gru_main, dim3(NBG * NCG), dim3(NTHR), 0, stream,
                     u, kfz, bfz, kr, br, wout, bout, out, ws);
}

// Round 4
// 13926.160 us; speedup vs baseline: 1.2736x; 1.2736x over previous
//
#include <hip/hip_runtime.h>
#include <stdint.h>

// Problem dims
#define B_    64
#define T_    2048
#define IN_   64
#define H_    512
#define H2_   1024
#define OUT_  32
#define KTOT  576          // IN_ + H_

// Grid: 256 blocks = 8 batch-groups x 32 col-groups, 256 threads.
#define NBG   8
#define NCG   32
#define NTHR  256
#define BPG   8            // batches per group
#define KSL   18           // k per slice (32 slices x 18 = 576)
#define RS    12           // bufA row stride in floats

// ws layout (32-bit words)
// Barriers are aggregated counters: one u32 per (bg, phase), spread 4KB apart
// so the 16 hot words map to DISTINCT memory channels (the old 64B-strided
// flag array packed 64 hot lines into ~2KB -> few channels -> queue blowup).
#define ABORT_IDX   0
#define CTR_OFF     1024                 // first counter, word offset (4KB)
#define CTR_STRIDE  1024                 // 4KB between counters
#define NCTR        (NBG * 2)            // 16 counters
#define BUF_BASE    (CTR_OFF + NCTR * CTR_STRIDE)   // 17408 (64B-aligned)
#define XSLAB       32768    // words per slab: [8 bg][512 j][8 b]

// ---- MALL-resident exchange primitives ----
// Publish: atomic swap (no sc0 -> no return) with sc1 -> executed AT the MALL
// (agent coherence point); line stays MALL-dirty, NOT written through to HBM.
// Trailing vmcnt(0) guarantees drain before the subsequent counter bump
// (compiler cannot track asm-issued VMEM in its own waitcnt insertion).
__device__ __forceinline__ void gpubf(float* p, float v) {
  asm volatile("global_atomic_swap %0, %1, off sc1\n\ts_waitcnt vmcnt(0)"
               :: "v"(p), "v"(v) : "memory");
}
// Counter bump: fire-and-forget one-way add at the MALL (no return, no drain
// needed on the publisher's critical path).
__device__ __forceinline__ void gaddu(unsigned* p, unsigned v) {
  asm volatile("global_atomic_add %0, %1, off sc1"
               :: "v"(p), "v"(v) : "memory");
}
// Coherent 4B poll load (bypasses stale L1/L2, reads the MALL).
__device__ __forceinline__ unsigned gpollu(const unsigned* p) {
  unsigned v;
  asm volatile("global_load_dword %0, %1, off sc0 sc1\n\ts_waitcnt vmcnt(0)"
               : "=v"(v) : "v"(p) : "memory");
  return v;
}
// Consume: MALL-coherent 16B loads, 4 in flight, one wait -> one latency
// exposure for the whole 32B-per-region stage.
__device__ __forceinline__ void gload4x4(const float* p0, const float* p1,
                                         const float* p2, const float* p3,
                                         float4& a, float4& b, float4& c, float4& d) {
  asm volatile(
      "global_load_dwordx4 %0, %4, off sc0 sc1\n\t"
      "global_load_dwordx4 %1, %5, off sc0 sc1\n\t"
      "global_load_dwordx4 %2, %6, off sc0 sc1\n\t"
      "global_load_dwordx4 %3, %7, off sc0 sc1\n\t"
      "s_waitcnt vmcnt(0)"
      : "=&v"(a), "=&v"(b), "=&v"(c), "=&v"(d)
      : "v"(p0), "v"(p1), "v"(p2), "v"(p3)
      : "memory");
}

__global__ __launch_bounds__(256) void gru_init(float* ws, const float* __restrict__ x0) {
  int i = blockIdx.x * blockDim.x + threadIdx.x;
  int stride = gridDim.x * blockDim.x;
  unsigned* w = (unsigned*)ws;
  for (int k = i; k < BUF_BASE; k += stride) w[k] = 0u;   // abort + counters
  // xg0[bg][j][b] = x0[(bg*8+b)*512 + j]
  for (int k = i; k < NBG * H_ * BPG; k += stride) {
    int bg = k >> 12, j = (k >> 3) & (H_ - 1), b = k & 7;
    ws[BUF_BASE + k] = x0[(bg * 8 + b) * H_ + j];
  }
}

// Arrive: all this block's data publishes already drained (gpubf waits), so
// after the block-local sync one lane bumps the group counter (one-way).
__device__ __forceinline__ void gbar_arrive(unsigned* ctr) {
  __syncthreads();
  if (threadIdx.x == 0) gaddu(ctr, 1u);
}

// Wait: ONE lane polls ONE counter word until it reaches 32*(t+1).
// 64B/round/block of poll traffic (was 2KB) on a 4KB-isolated line.
__device__ __forceinline__ bool gbar_wait(unsigned* ctr, unsigned target,
                                          unsigned* abort_w) {
  __shared__ int s_ok;
  if (threadIdx.x == 0) {
    int ok = 1;
    int polls = 0;
    while (gpollu(ctr) < target) {
      __builtin_amdgcn_s_sleep(1);
      if ((++polls & 255) == 0) {
        if (__hip_atomic_load(abort_w, __ATOMIC_RELAXED, __HIP_MEMORY_SCOPE_AGENT) != 0u ||
            polls > 2000000) {
          __hip_atomic_store(abort_w, 1u, __ATOMIC_RELAXED, __HIP_MEMORY_SCOPE_AGENT);
          ok = 0;
          break;
        }
      }
    }
    s_ok = ok;
  }
  __syncthreads();
  __atomic_signal_fence(__ATOMIC_ACQUIRE);  // compiler reordering guard only
  return s_ok != 0;
}

__global__ __launch_bounds__(NTHR, 1) void gru_main(
    const float* __restrict__ u, const float* __restrict__ kfz,
    const float* __restrict__ bfz, const float* __restrict__ kr,
    const float* __restrict__ br, const float* __restrict__ wout,
    const float* __restrict__ bout, float* __restrict__ out, float* ws) {
  unsigned* wsu = (unsigned*)ws;
  unsigned* abort_w = wsu + ABORT_IDX;
  float* xg0 = ws + BUF_BASE;
  float* xg1 = xg0 + XSLAB;
  float* xfg = xg1 + XSLAB;

  const int bg  = blockIdx.x & 7;
  const int cg  = blockIdx.x >> 3;   // column group 0..31
  const int tid = threadIdx.x;
  const int w   = tid >> 6;          // wave 0..3
  const int l   = tid & 63;
  const int cq  = l & 7;             // col-quad 0..7
  const int g   = l >> 3;            // in-wave k-slice 0..7
  const int kb  = (w * 8 + g) * KSL; // this thread's k base (18 k's)
  const int fc  = tid >> 3;          // finalize col 0..31
  const int fb  = tid & 7;           // finalize batch 0..7
  const int yb  = tid >> 5;          // y batch 0..7
  const int yq  = tid & 31;          // y k-slice 0..31

  unsigned* ctrA = wsu + CTR_OFF + (bg * 2 + 0) * CTR_STRIDE;
  unsigned* ctrB = wsu + CTR_OFF + (bg * 2 + 1) * CTR_STRIDE;

  __shared__ float bufA[KTOT * RS];  // [k][12]: u_t(k<64) | x or f*x
  __shared__ float pA[4 * 32 * RS];
  __shared__ float pB[4 * 16 * RS];
  __shared__ float rbuf[16 * 8];

  // ---- one-time: weights into registers ----
  float wA[KSL][4];
#pragma unroll
  for (int i = 0; i < KSL; ++i)
#pragma unroll
    for (int m = 0; m < 4; ++m) {
      int c = 4 * cq + m;
      int gcol = (c < 16) ? (16 * cg + c) : (512 + 16 * cg + (c - 16));
      wA[i][m] = kfz[(size_t)(kb + i) * H2_ + gcol];
    }
  float wB[KSL][2];
#pragma unroll
  for (int i = 0; i < KSL; ++i)
#pragma unroll
    for (int m = 0; m < 2; ++m)
      wB[i][m] = kr[(size_t)(kb + i) * H_ + (16 * cg + 2 * cq + m)];
  float wy[16];
#pragma unroll
  for (int i = 0; i < 16; ++i) wy[i] = wout[cg * H_ + (yq + 32 * i)];
  const float by = bout[cg];
  const int fzc = (fc < 16) ? (16 * cg + fc) : (512 + 16 * cg + (fc - 16));
  const float biasA = bfz[fzc];
  const float biasB = (tid < 128) ? br[16 * cg + fc] : 0.0f;

  float zreg = 0.0f, xoldz = 0.0f;

  // u_t=0 into LDS (later steps prefetched during barrier-2 window)
  {
    int k2 = tid & 31, b = tid >> 5;
    float2 uv = *(const float2*)&u[((size_t)(bg * 8 + b) * T_) * IN_ + 2 * k2];
    bufA[(2 * k2) * RS + b] = uv.x;
    bufA[(2 * k2 + 1) * RS + b] = uv.y;
  }

  for (int t = 0; t < T_; ++t) {
    float* xcur = (t & 1) ? xg1 : xg0;
    float* xnxt = (t & 1) ? xg0 : xg1;

    // ---- stage x into bufA (MALL-coherent dwordx4; b128 LDS writes) ----
    {
      const float* s0 = &xcur[(size_t)(bg * H_ + tid) * 8];
      const float* s2 = &xcur[(size_t)(bg * H_ + tid + 256) * 8];
      float4 a, b, c, d;
      gload4x4(s0, s0 + 4, s2, s2 + 4, a, b, c, d);
      *(float4*)&bufA[(64 + tid) * RS] = a;
      *(float4*)&bufA[(64 + tid) * RS + 4] = b;
      *(float4*)&bufA[(64 + tid + 256) * RS] = c;
      *(float4*)&bufA[(64 + tid + 256) * RS + 4] = d;
    }
    __syncthreads();

    // ---- phase A core: fz partials for 4 cols x 8 batches over 18 k ----
    float acc[4][8] = {};
#pragma unroll
    for (int i = 0; i < KSL; ++i) {
      const float* xr = &bufA[(kb + i) * RS];
      float4 x0 = *(const float4*)xr;
      float4 x1 = *(const float4*)(xr + 4);
#pragma unroll
      for (int m = 0; m < 4; ++m) {
        float wv = wA[i][m];
        acc[m][0] += wv * x0.x; acc[m][1] += wv * x0.y;
        acc[m][2] += wv * x0.z; acc[m][3] += wv * x0.w;
        acc[m][4] += wv * x1.x; acc[m][5] += wv * x1.y;
        acc[m][6] += wv * x1.z; acc[m][7] += wv * x1.w;
      }
    }

    // ---- reduce A ----
#pragma unroll
    for (int m = 0; m < 4; ++m)
#pragma unroll
      for (int b = 0; b < 8; ++b) {
        acc[m][b] += __shfl_xor(acc[m][b], 8);
        acc[m][b] += __shfl_xor(acc[m][b], 16);
        acc[m][b] += __shfl_xor(acc[m][b], 32);
      }
    if (g == 0) {
#pragma unroll
      for (int m = 0; m < 4; ++m) {
        float* p = &pA[(w * 32 + 4 * cq + m) * RS];
        *(float4*)p = make_float4(acc[m][0], acc[m][1], acc[m][2], acc[m][3]);
        *(float4*)(p + 4) = make_float4(acc[m][4], acc[m][5], acc[m][6], acc[m][7]);
      }
    }
    __syncthreads();

    // ---- finalize A: sigmoid; publish f*x (MALL atomic swap); stash z ----
    {
      float s = pA[(0 * 32 + fc) * RS + fb] + pA[(1 * 32 + fc) * RS + fb] +
                pA[(2 * 32 + fc) * RS + fb] + pA[(3 * 32 + fc) * RS + fb] + biasA;
      float sig = 1.0f / (1.0f + __expf(-s));
      if (fc < 16) {
        float xo = bufA[(64 + 16 * cg + fc) * RS + fb];
        gpubf(&xfg[(size_t)(bg * H_ + 16 * cg + fc) * 8 + fb], sig * xo);
      } else {
        zreg = sig;
        xoldz = bufA[(64 + 16 * cg + (fc - 16)) * RS + fb];
      }
    }

    gbar_arrive(ctrA);

    // ---- y_t = x_t @ wout[cg]: overlapped with barrier-1 poll latency ----
    {
      float yp = 0.0f;
#pragma unroll
      for (int i = 0; i < 16; ++i)
        yp += wy[i] * bufA[(64 + yq + 32 * i) * RS + yb];
      yp += __shfl_xor(yp, 1);  yp += __shfl_xor(yp, 2);
      yp += __shfl_xor(yp, 4);  yp += __shfl_xor(yp, 8);
      yp += __shfl_xor(yp, 16);
      if (yq == 0)
        out[((size_t)(bg * 8 + yb) * T_ + t) * OUT_ + cg] = yp + by;
    }

    if (!gbar_wait(ctrA, (unsigned)(NCG * (t + 1)), abort_w)) return;

    // ---- stage f*x into bufA (MALL-coherent dwordx4) ----
    {
      const float* s0 = &xfg[(size_t)(bg * H_ + tid) * 8];
      const float* s2 = &xfg[(size_t)(bg * H_ + tid + 256) * 8];
      float4 a, b, c, d;
      gload4x4(s0, s0 + 4, s2, s2 + 4, a, b, c, d);
      *(float4*)&bufA[(64 + tid) * RS] = a;
      *(float4*)&bufA[(64 + tid) * RS + 4] = b;
      *(float4*)&bufA[(64 + tid + 256) * RS] = c;
      *(float4*)&bufA[(64 + tid + 256) * RS + 4] = d;
    }
    __syncthreads();

    // ---- phase B core: r partials for 2 cols x 8 batches ----
    float acc2[2][8] = {};
#pragma unroll
    for (int i = 0; i < KSL; ++i) {
      const float* xr = &bufA[(kb + i) * RS];
      float4 x0 = *(const float4*)xr;
      float4 x1 = *(const float4*)(xr + 4);
#pragma unroll
      for (int m = 0; m < 2; ++m) {
        float wv = wB[i][m];
        acc2[m][0] += wv * x0.x; acc2[m][1] += wv * x0.y;
        acc2[m][2] += wv * x0.z; acc2[m][3] += wv * x0.w;
        acc2[m][4] += wv * x1.x; acc2[m][5] += wv * x1.y;
        acc2[m][6] += wv * x1.z; acc2[m][7] += wv * x1.w;
      }
    }
#pragma unroll
    for (int m = 0; m < 2; ++m)
#pragma unroll
      for (int b = 0; b < 8; ++b) {
        acc2[m][b] += __shfl_xor(acc2[m][b], 8);
        acc2[m][b] += __shfl_xor(acc2[m][b], 16);
        acc2[m][b] += __shfl_xor(acc2[m][b], 32);
      }
    if (g == 0) {
#pragma unroll
      for (int m = 0; m < 2; ++m) {
        float* p = &pB[(w * 16 + 2 * cq + m) * RS];
        *(float4*)p = make_float4(acc2[m][0], acc2[m][1], acc2[m][2], acc2[m][3]);
        *(float4*)(p + 4) = make_float4(acc2[m][4], acc2[m][5], acc2[m][6], acc2[m][7]);
      }
    }
    __syncthreads();

    // ---- finalize B: tanh -> rbuf ----
    if (tid < 128) {
      float s = pB[(0 * 16 + fc) * RS + fb] + pB[(1 * 16 + fc) * RS + fb] +
                pB[(2 * 16 + fc) * RS + fb] + pB[(3 * 16 + fc) * RS + fb] + biasB;
      float e = __expf(2.0f * s);
      rbuf[fc * 8 + fb] = 1.0f - 2.0f / (1.0f + e);
    }
    __syncthreads();

    // ---- update: x_next = x + z*(r - x) (MALL atomic swap) ----
    if (tid >= 128) {
      float r = rbuf[(fc - 16) * 8 + fb];
      float xn = xoldz + zreg * (r - xoldz);
      gpubf(&xnxt[(size_t)(bg * H_ + 16 * cg + (fc - 16)) * 8 + fb], xn);
    }

    gbar_arrive(ctrB);

    // ---- prefetch u_{t+1} into LDS while barrier-2 resolves ----
    if (t + 1 < T_) {
      int k2 = tid & 31, b = tid >> 5;
      float2 uv = *(const float2*)&u[((size_t)(bg * 8 + b) * T_ + (t + 1)) * IN_ + 2 * k2];
      bufA[(2 * k2) * RS + b] = uv.x;
      bufA[(2 * k2 + 1) * RS + b] = uv.y;
    }

    if (!gbar_wait(ctrB, (unsigned)(NCG * (t + 1)), abort_w)) return;
  }
}

extern "C" void kernel_launch(void* const* d_in, const int* in_sizes, int n_in,
                              void* d_out, int out_size, void* d_ws, size_t ws_size,
                              hipStream_t stream) {
  const float* u    = (const float*)d_in[0];
  const float* x0   = (const float*)d_in[1];
  const float* kfz  = (const float*)d_in[2];
  const float* bfz  = (const float*)d_in[3];
  const float* kr   = (const float*)d_in[4];
  const float* br   = (const float*)d_in[5];
  const float* wout = (const float*)d_in[6];
  const float* bout = (const float*)d_in[7];
  float* out = (float*)d_out;
  float* ws  = (float*)d_ws;

  hipLaunchKernelGGL(gru_init, dim3(64), dim3(256), 0, stream, ws, x0);
  hipLaunchKernelGGL(gru_main, dim3(NBG * NCG), dim3(NTHR), 0, stream,
                     u, kfz, bfz, kr, br, wout, bout, out, ws);
}